// Round 5
// baseline (314.929 us; speedup 1.0000x reference)
//
#include <hip/hip_runtime.h>
#include <math.h>

#define Bb 8
#define Nn 4096
#define Dd 768
#define PADDED 1024
#define D4 192        // Dd/4
#define NCHUNK 128    // n-chunks for the mean reduction
#define ROWS (Nn / NCHUNK)   // 32 rows per chunk

typedef float floatx4 __attribute__((ext_vector_type(4)));   // native vec for nontemporal builtins

// ---------------- kernel 1a: partial column sums (no atomics) ----------------
// grid: Bb*NCHUNK = 1024 blocks, 192 threads. partial[k][b][d] in ws.
__global__ __launch_bounds__(192) void k_colsum_part(const float4* __restrict__ x4,
                                                     float* __restrict__ partial) {
    int bid = blockIdx.x;
    int b = bid >> 7;              // /NCHUNK
    int k = bid & (NCHUNK - 1);
    int t = threadIdx.x;           // 0..191
    const float4* p = x4 + ((size_t)(b * Nn + k * ROWS) * D4) + t;
    float4 acc = {0.f, 0.f, 0.f, 0.f};
#pragma unroll 8
    for (int r = 0; r < ROWS; ++r) {
        float4 v = p[(size_t)r * D4];
        acc.x += v.x; acc.y += v.y; acc.z += v.z; acc.w += v.w;
    }
    float4* dst = (float4*)(partial + ((size_t)k * Bb + b) * Dd) + t;
    *dst = acc;
}

// ---------------- kernel 1b: atomic fallback (tiny ws) ----------------
__global__ __launch_bounds__(192) void k_colsum_atomic(const float4* __restrict__ x4,
                                                       float* __restrict__ c_sum) {
    int bid = blockIdx.x;
    int b = bid >> 7;
    int k = bid & (NCHUNK - 1);
    int t = threadIdx.x;
    const float4* p = x4 + ((size_t)(b * Nn + k * ROWS) * D4) + t;
    float4 acc = {0.f, 0.f, 0.f, 0.f};
#pragma unroll 8
    for (int r = 0; r < ROWS; ++r) {
        float4 v = p[(size_t)r * D4];
        acc.x += v.x; acc.y += v.y; acc.z += v.z; acc.w += v.w;
    }
    float* cs = c_sum + b * Dd + t * 4;
    atomicAdd(cs + 0, acc.x);
    atomicAdd(cs + 1, acc.y);
    atomicAdd(cs + 2, acc.z);
    atomicAdd(cs + 3, acc.w);
}

// ------------- kernel 2: reduce chunks + WHT + weight + GEMV + sigmoid -------------
// grid: Bb blocks, PADDED(=1024) threads. cw never leaves LDS.
// src layout: [nchunks][Bb][Dd]; nchunks==1 for the atomic path.
__global__ __launch_bounds__(PADDED) void k_whtgate(const float* __restrict__ src, int nchunks,
                                                    const float* __restrict__ wht_weight,
                                                    const float4* __restrict__ gw4,
                                                    const float* __restrict__ gate_b,
                                                    float* __restrict__ gate) {
    __shared__ float s[PADDED];
    int b = blockIdx.x;
    int t = threadIdx.x;
    float v = 0.f;
    if (t < Dd) {
        float acc = 0.f;
        for (int k = 0; k < nchunks; ++k)
            acc += src[((size_t)k * Bb + b) * Dd + t];
        v = acc * (1.0f / (float)Nn);   // mean
    }
    s[t] = v;                            // zero-pad 768..1023
    __syncthreads();
    // 10-stage butterfly; matches the reference's reshape/stack ordering:
    //   bit clear: self + partner(t+st);  bit set: partner(t-st) - self
    for (int st = 1; st < PADDED; st <<= 1) {
        float a = s[t];
        float p = s[t ^ st];
        __syncthreads();
        s[t] = (t & st) ? (p - a) : (a + p);
        __syncthreads();
    }
    s[t] = s[t] * (1.0f / (float)PADDED) * wht_weight[t];
    __syncthreads();
    // gate[b][t] = sigmoid(dot(s, gate_w[t,:]) + gate_b[t]) for t < 768
    if (t < Dd) {
        const float4* w = gw4 + (size_t)t * (PADDED / 4);
        float acc = 0.f;
#pragma unroll 8
        for (int p = 0; p < PADDED / 4; ++p) {
            float4 wv = w[p];
            acc += s[4 * p] * wv.x + s[4 * p + 1] * wv.y
                 + s[4 * p + 2] * wv.z + s[4 * p + 3] * wv.w;
        }
        float z = acc + gate_b[t];
        gate[b * Dd + t] = 1.0f / (1.0f + expf(-z));
    }
}

// ---------------- kernel 3: out = x * gate ----------------
// grid: Bb*256 = 2048 blocks, 192 threads; 16 rows per block, gate held in-register.
// Nontemporal stores keep x resident in L3 for this second read.
__global__ __launch_bounds__(192) void k_scale(const floatx4* __restrict__ x4,
                                               const floatx4* __restrict__ gate4,
                                               floatx4* __restrict__ out4) {
    int bid = blockIdx.x;
    int b = bid >> 8;              // /256
    int n0 = (bid & 255) * 16;
    int t = threadIdx.x;           // 0..191
    floatx4 g = gate4[b * D4 + t];
    size_t base = ((size_t)(b * Nn + n0) * D4) + t;
#pragma unroll
    for (int r = 0; r < 16; ++r) {
        floatx4 v = x4[base + (size_t)r * D4];
        floatx4 o = v * g;
        __builtin_nontemporal_store(o, &out4[base + (size_t)r * D4]);
    }
}

extern "C" void kernel_launch(void* const* d_in, const int* in_sizes, int n_in,
                              void* d_out, int out_size, void* d_ws, size_t ws_size,
                              hipStream_t stream) {
    const float* x          = (const float*)d_in[0];
    const float* wht_weight = (const float*)d_in[1];
    const float* gate_w     = (const float*)d_in[2];
    const float* gate_b     = (const float*)d_in[3];
    float* out = (float*)d_out;

    // ws layout (big path): partial [NCHUNK][Bb][Dd] | gate [Bb][Dd]
    size_t need_big = ((size_t)NCHUNK * Bb * Dd + (size_t)Bb * Dd) * 4;
    float* wsf = (float*)d_ws;

    if (ws_size >= need_big) {
        float* partial = wsf;
        float* gate = partial + (size_t)NCHUNK * Bb * Dd;
        k_colsum_part<<<Bb * NCHUNK, 192, 0, stream>>>((const float4*)x, partial);
        k_whtgate<<<Bb, PADDED, 0, stream>>>(partial, NCHUNK, wht_weight,
                                             (const float4*)gate_w, gate_b, gate);
        k_scale<<<Bb * 256, 192, 0, stream>>>((const floatx4*)x, (const floatx4*)gate, (floatx4*)out);
    } else {
        // tiny-ws fallback: atomics into c_sum
        float* c_sum = wsf;                       // Bb*Dd
        float* gate  = c_sum + (size_t)Bb * Dd;   // Bb*Dd
        (void)hipMemsetAsync(c_sum, 0, (size_t)Bb * Dd * sizeof(float), stream);
        k_colsum_atomic<<<Bb * NCHUNK, 192, 0, stream>>>((const float4*)x, c_sum);
        k_whtgate<<<Bb, PADDED, 0, stream>>>(c_sum, 1, wht_weight,
                                             (const float4*)gate_w, gate_b, gate);
        k_scale<<<Bb * 256, 192, 0, stream>>>((const floatx4*)x, (const floatx4*)gate, (floatx4*)out);
    }
}

// Round 6
// 281.312 us; speedup vs baseline: 1.1195x; 1.1195x over previous
//
#include <hip/hip_runtime.h>
#include <math.h>

#define Bb 8
#define Nn 4096
#define Dd 768
#define PADDED 1024
#define D4 192        // Dd/4
#define P4 256        // PADDED/4
#define NCHUNK 128    // n-chunks for the mean reduction
#define ROWS (Nn / NCHUNK)   // 32 rows per chunk

typedef float floatx4 __attribute__((ext_vector_type(4)));   // native vec for nontemporal builtins

// ---------------- kernel 1a: partial column sums (no atomics) ----------------
// grid: Bb*NCHUNK = 1024 blocks, 192 threads. partial[k][b][d] in ws.
__global__ __launch_bounds__(192) void k_colsum_part(const float4* __restrict__ x4,
                                                     float* __restrict__ partial) {
    int bid = blockIdx.x;
    int b = bid >> 7;              // /NCHUNK
    int k = bid & (NCHUNK - 1);
    int t = threadIdx.x;           // 0..191
    const float4* p = x4 + ((size_t)(b * Nn + k * ROWS) * D4) + t;
    float4 acc = {0.f, 0.f, 0.f, 0.f};
#pragma unroll 8
    for (int r = 0; r < ROWS; ++r) {
        float4 v = p[(size_t)r * D4];
        acc.x += v.x; acc.y += v.y; acc.z += v.z; acc.w += v.w;
    }
    float4* dst = (float4*)(partial + ((size_t)k * Bb + b) * Dd) + t;
    *dst = acc;
}

// ---------------- kernel 1b: atomic fallback (tiny ws) ----------------
__global__ __launch_bounds__(192) void k_colsum_atomic(const float4* __restrict__ x4,
                                                       float* __restrict__ c_sum) {
    int bid = blockIdx.x;
    int b = bid >> 7;
    int k = bid & (NCHUNK - 1);
    int t = threadIdx.x;
    const float4* p = x4 + ((size_t)(b * Nn + k * ROWS) * D4) + t;
    float4 acc = {0.f, 0.f, 0.f, 0.f};
#pragma unroll 8
    for (int r = 0; r < ROWS; ++r) {
        float4 v = p[(size_t)r * D4];
        acc.x += v.x; acc.y += v.y; acc.z += v.z; acc.w += v.w;
    }
    float* cs = c_sum + b * Dd + t * 4;
    atomicAdd(cs + 0, acc.x);
    atomicAdd(cs + 1, acc.y);
    atomicAdd(cs + 2, acc.z);
    atomicAdd(cs + 3, acc.w);
}

// ------------- kernel 2: reduce chunks + WHT + weight -> cw[Bb][PADDED] -------------
// grid: Bb blocks, PADDED(=1024) threads.
// src layout: [nchunks][Bb][Dd]; nchunks==1 for the atomic path.
__global__ __launch_bounds__(PADDED) void k_wht(const float* __restrict__ src, int nchunks,
                                                const float* __restrict__ wht_weight,
                                                float* __restrict__ cw) {
    __shared__ float s[PADDED];
    int b = blockIdx.x;
    int t = threadIdx.x;
    float v = 0.f;
    if (t < Dd) {
        float acc = 0.f;
#pragma unroll 8
        for (int k = 0; k < nchunks; ++k)
            acc += src[((size_t)k * Bb + b) * Dd + t];
        v = acc * (1.0f / (float)Nn);   // mean
    }
    s[t] = v;                            // zero-pad 768..1023
    __syncthreads();
    // 10-stage butterfly; matches the reference's reshape/stack ordering:
    //   bit clear: self + partner(t+st);  bit set: partner(t-st) - self
    for (int st = 1; st < PADDED; st <<= 1) {
        float a = s[t];
        float p = s[t ^ st];
        __syncthreads();
        s[t] = (t & st) ? (p - a) : (a + p);
        __syncthreads();
    }
    cw[b * PADDED + t] = s[t] * (1.0f / (float)PADDED) * wht_weight[t];
}

// ------------- kernel 3: gate = sigmoid(cw @ gate_w.T + gate_b) -------------
// grid: 12 blocks x 64 threads. One thread per output row d; b-loop innermost.
// gate_w row read per-lane-sequentially (L1 line reuse); cw read at block-uniform
// addresses (scalar cache / broadcast). gate_w traffic = 3 MB total, read once.
__global__ __launch_bounds__(64) void k_gate(const float4* __restrict__ cw4,
                                             const float4* __restrict__ gw4,
                                             const float* __restrict__ gate_b,
                                             float* __restrict__ gate) {
    int d = blockIdx.x * 64 + threadIdx.x;   // 0..767
    const float4* w = gw4 + (size_t)d * P4;
    float acc[Bb];
#pragma unroll
    for (int b = 0; b < Bb; ++b) acc[b] = 0.f;
#pragma unroll 4
    for (int seg = 0; seg < P4; ++seg) {
        float4 wv = w[seg];
#pragma unroll
        for (int b = 0; b < Bb; ++b) {
            float4 c = cw4[b * P4 + seg];    // uniform across block
            acc[b] += wv.x * c.x + wv.y * c.y + wv.z * c.z + wv.w * c.w;
        }
    }
    float bias = gate_b[d];
#pragma unroll
    for (int b = 0; b < Bb; ++b) {
        float z = acc[b] + bias;
        gate[b * Dd + d] = 1.0f / (1.0f + expf(-z));
    }
}

// ---------------- kernel 4: out = x * gate ----------------
// grid: Bb*256 = 2048 blocks, 192 threads; 16 rows per block, gate held in-register.
// Nontemporal stores keep x resident in L3 for this second read.
__global__ __launch_bounds__(192) void k_scale(const floatx4* __restrict__ x4,
                                               const floatx4* __restrict__ gate4,
                                               floatx4* __restrict__ out4) {
    int bid = blockIdx.x;
    int b = bid >> 8;              // /256
    int n0 = (bid & 255) * 16;
    int t = threadIdx.x;           // 0..191
    floatx4 g = gate4[b * D4 + t];
    size_t base = ((size_t)(b * Nn + n0) * D4) + t;
#pragma unroll
    for (int r = 0; r < 16; ++r) {
        floatx4 v = x4[base + (size_t)r * D4];
        floatx4 o = v * g;
        __builtin_nontemporal_store(o, &out4[base + (size_t)r * D4]);
    }
}

extern "C" void kernel_launch(void* const* d_in, const int* in_sizes, int n_in,
                              void* d_out, int out_size, void* d_ws, size_t ws_size,
                              hipStream_t stream) {
    const float* x          = (const float*)d_in[0];
    const float* wht_weight = (const float*)d_in[1];
    const float* gate_w     = (const float*)d_in[2];
    const float* gate_b     = (const float*)d_in[3];
    float* out = (float*)d_out;

    // ws layout (big path): partial [NCHUNK][Bb][Dd] | cw [Bb][PADDED] | gate [Bb][Dd]
    size_t need_big = ((size_t)NCHUNK * Bb * Dd + (size_t)Bb * PADDED + (size_t)Bb * Dd) * 4;
    float* wsf = (float*)d_ws;

    if (ws_size >= need_big) {
        float* partial = wsf;
        float* cw   = partial + (size_t)NCHUNK * Bb * Dd;
        float* gate = cw + (size_t)Bb * PADDED;
        k_colsum_part<<<Bb * NCHUNK, 192, 0, stream>>>((const float4*)x, partial);
        k_wht<<<Bb, PADDED, 0, stream>>>(partial, NCHUNK, wht_weight, cw);
        k_gate<<<12, 64, 0, stream>>>((const float4*)cw, (const float4*)gate_w, gate_b, gate);
        k_scale<<<Bb * 256, 192, 0, stream>>>((const floatx4*)x, (const floatx4*)gate, (floatx4*)out);
    } else {
        // tiny-ws fallback: atomics into c_sum
        float* c_sum = wsf;                       // Bb*Dd
        float* cw    = c_sum + (size_t)Bb * Dd;   // Bb*PADDED
        float* gate  = cw + (size_t)Bb * PADDED;  // Bb*Dd
        (void)hipMemsetAsync(c_sum, 0, (size_t)Bb * Dd * sizeof(float), stream);
        k_colsum_atomic<<<Bb * NCHUNK, 192, 0, stream>>>((const float4*)x, c_sum);
        k_wht<<<Bb, PADDED, 0, stream>>>(c_sum, 1, wht_weight, cw);
        k_gate<<<12, 64, 0, stream>>>((const float4*)cw, (const float4*)gate_w, gate_b, gate);
        k_scale<<<Bb * 256, 192, 0, stream>>>((const floatx4*)x, (const floatx4*)gate, (floatx4*)out);
    }
}

// Round 7
// 212.318 us; speedup vs baseline: 1.4833x; 1.3250x over previous
//
#include <hip/hip_runtime.h>
#include <math.h>

#define Bb 8
#define Nn 4096
#define Dd 768
#define PADDED 1024
#define D4 192        // Dd/4
#define P4 256        // PADDED/4
#define NCHUNK 128    // n-chunks for the mean reduction
#define ROWS (Nn / NCHUNK)   // 32 rows per chunk

typedef float floatx4 __attribute__((ext_vector_type(4)));   // native vec for nontemporal builtins

// ---------------- kernel 1a: partial column sums (no atomics) ----------------
// grid: Bb*NCHUNK = 1024 blocks, 192 threads. partial[k][b][d] in ws.
__global__ __launch_bounds__(192) void k_colsum_part(const float4* __restrict__ x4,
                                                     float* __restrict__ partial) {
    int bid = blockIdx.x;
    int b = bid >> 7;              // /NCHUNK
    int k = bid & (NCHUNK - 1);
    int t = threadIdx.x;           // 0..191
    const float4* p = x4 + ((size_t)(b * Nn + k * ROWS) * D4) + t;
    float4 acc = {0.f, 0.f, 0.f, 0.f};
#pragma unroll 8
    for (int r = 0; r < ROWS; ++r) {
        float4 v = p[(size_t)r * D4];
        acc.x += v.x; acc.y += v.y; acc.z += v.z; acc.w += v.w;
    }
    float4* dst = (float4*)(partial + ((size_t)k * Bb + b) * Dd) + t;
    *dst = acc;
}

// ---------------- kernel 1b: atomic fallback (tiny ws) ----------------
__global__ __launch_bounds__(192) void k_colsum_atomic(const float4* __restrict__ x4,
                                                       float* __restrict__ c_sum) {
    int bid = blockIdx.x;
    int b = bid >> 7;
    int k = bid & (NCHUNK - 1);
    int t = threadIdx.x;
    const float4* p = x4 + ((size_t)(b * Nn + k * ROWS) * D4) + t;
    float4 acc = {0.f, 0.f, 0.f, 0.f};
#pragma unroll 8
    for (int r = 0; r < ROWS; ++r) {
        float4 v = p[(size_t)r * D4];
        acc.x += v.x; acc.y += v.y; acc.z += v.z; acc.w += v.w;
    }
    float* cs = c_sum + b * Dd + t * 4;
    atomicAdd(cs + 0, acc.x);
    atomicAdd(cs + 1, acc.y);
    atomicAdd(cs + 2, acc.z);
    atomicAdd(cs + 3, acc.w);
}

// ------------- kernel 2: reduce chunks + WHT + weight -> cw[Bb][PADDED] -------------
// grid: Bb blocks, PADDED(=1024) threads.
// src layout: [nchunks][Bb][Dd]; nchunks==1 for the atomic path.
__global__ __launch_bounds__(PADDED) void k_wht(const float* __restrict__ src, int nchunks,
                                                const float* __restrict__ wht_weight,
                                                float* __restrict__ cw) {
    __shared__ float s[PADDED];
    int b = blockIdx.x;
    int t = threadIdx.x;
    float v = 0.f;
    if (t < Dd) {
        float acc = 0.f;
#pragma unroll 8
        for (int k = 0; k < nchunks; ++k)
            acc += src[((size_t)k * Bb + b) * Dd + t];
        v = acc * (1.0f / (float)Nn);   // mean
    }
    s[t] = v;                            // zero-pad 768..1023
    __syncthreads();
    // 10-stage butterfly; matches the reference's reshape/stack ordering:
    //   bit clear: self + partner(t+st);  bit set: partner(t-st) - self
    for (int st = 1; st < PADDED; st <<= 1) {
        float a = s[t];
        float p = s[t ^ st];
        __syncthreads();
        s[t] = (t & st) ? (p - a) : (a + p);
        __syncthreads();
    }
    cw[b * PADDED + t] = s[t] * (1.0f / (float)PADDED) * wht_weight[t];
}

// ------------- kernel 3: gate = sigmoid(cw @ gate_w.T + gate_b) -------------
// grid: 1536 blocks x 256 threads = 6144 waves; ONE WAVE PER OUTPUT (b,d).
// Each wave: 4 coalesced float4 loads/lane from gate_w row + 4 from cw row
// (8 independent loads in flight), shfl_xor tree reduce, sigmoid, 1 store.
__global__ __launch_bounds__(256) void k_gate(const float4* __restrict__ cw4,
                                              const float4* __restrict__ gw4,
                                              const float* __restrict__ gate_b,
                                              float* __restrict__ gate) {
    int wave = (blockIdx.x * 256 + threadIdx.x) >> 6;   // 0..6143
    int lane = threadIdx.x & 63;
    int d = wave >> 3;        // 0..767
    int b = wave & 7;         // 0..7
    const float4* w = gw4 + (size_t)d * P4;
    const float4* c = cw4 + (size_t)b * P4;
    float acc = 0.f;
#pragma unroll
    for (int j = 0; j < 4; ++j) {
        int seg = lane + 64 * j;
        float4 wv = w[seg];
        float4 cv = c[seg];
        acc += wv.x * cv.x + wv.y * cv.y + wv.z * cv.z + wv.w * cv.w;
    }
#pragma unroll
    for (int off = 32; off > 0; off >>= 1)
        acc += __shfl_xor(acc, off, 64);
    if (lane == 0) {
        float z = acc + gate_b[d];
        gate[b * Dd + d] = 1.0f / (1.0f + expf(-z));
    }
}

// ---------------- kernel 4: out = x * gate ----------------
// grid: Bb*256 = 2048 blocks, 192 threads; 16 rows per block, gate held in-register.
// Nontemporal stores keep x resident in L3 for this second read.
__global__ __launch_bounds__(192) void k_scale(const floatx4* __restrict__ x4,
                                               const floatx4* __restrict__ gate4,
                                               floatx4* __restrict__ out4) {
    int bid = blockIdx.x;
    int b = bid >> 8;              // /256
    int n0 = (bid & 255) * 16;
    int t = threadIdx.x;           // 0..191
    floatx4 g = gate4[b * D4 + t];
    size_t base = ((size_t)(b * Nn + n0) * D4) + t;
#pragma unroll
    for (int r = 0; r < 16; ++r) {
        floatx4 v = x4[base + (size_t)r * D4];
        floatx4 o = v * g;
        __builtin_nontemporal_store(o, &out4[base + (size_t)r * D4]);
    }
}

extern "C" void kernel_launch(void* const* d_in, const int* in_sizes, int n_in,
                              void* d_out, int out_size, void* d_ws, size_t ws_size,
                              hipStream_t stream) {
    const float* x          = (const float*)d_in[0];
    const float* wht_weight = (const float*)d_in[1];
    const float* gate_w     = (const float*)d_in[2];
    const float* gate_b     = (const float*)d_in[3];
    float* out = (float*)d_out;

    // ws layout (big path): partial [NCHUNK][Bb][Dd] | cw [Bb][PADDED] | gate [Bb][Dd]
    size_t need_big = ((size_t)NCHUNK * Bb * Dd + (size_t)Bb * PADDED + (size_t)Bb * Dd) * 4;
    float* wsf = (float*)d_ws;

    if (ws_size >= need_big) {
        float* partial = wsf;
        float* cw   = partial + (size_t)NCHUNK * Bb * Dd;
        float* gate = cw + (size_t)Bb * PADDED;
        k_colsum_part<<<Bb * NCHUNK, 192, 0, stream>>>((const float4*)x, partial);
        k_wht<<<Bb, PADDED, 0, stream>>>(partial, NCHUNK, wht_weight, cw);
        k_gate<<<1536, 256, 0, stream>>>((const float4*)cw, (const float4*)gate_w, gate_b, gate);
        k_scale<<<Bb * 256, 192, 0, stream>>>((const floatx4*)x, (const floatx4*)gate, (floatx4*)out);
    } else {
        // tiny-ws fallback: atomics into c_sum
        float* c_sum = wsf;                       // Bb*Dd
        float* cw    = c_sum + (size_t)Bb * Dd;   // Bb*PADDED
        float* gate  = cw + (size_t)Bb * PADDED;  // Bb*Dd
        (void)hipMemsetAsync(c_sum, 0, (size_t)Bb * Dd * sizeof(float), stream);
        k_colsum_atomic<<<Bb * NCHUNK, 192, 0, stream>>>((const float4*)x, c_sum);
        k_wht<<<Bb, PADDED, 0, stream>>>(c_sum, 1, wht_weight, cw);
        k_gate<<<1536, 256, 0, stream>>>((const float4*)cw, (const float4*)gate_w, gate_b, gate);
        k_scale<<<Bb * 256, 192, 0, stream>>>((const floatx4*)x, (const floatx4*)gate, (floatx4*)out);
    }
}